// Round 5
// baseline (452.367 us; speedup 1.0000x reference)
//
#include <hip/hip_runtime.h>
#include <math.h>

// ---------------- config ----------------
// JAX dropout RNG: jax_threefry_partitionable scheme (verified correct R1).
// Layer keys are compile-time constants (constexpr threefry of key(42) split).

#define Bsz 4
#define Nn  4096
#define Dd  64
#define TOT (Bsz*Nn*Dd)          // 1048576

typedef unsigned int u32;
typedef unsigned long long u64;
typedef short short8 __attribute__((ext_vector_type(8)));
typedef float f32x4 __attribute__((ext_vector_type(4)));

// ---------------- helpers ----------------
__device__ __forceinline__ unsigned short bf16_of(float x) {
  u32 u = __float_as_uint(x);
  u32 r = (u + 0x7FFFu + ((u >> 16) & 1u)) >> 16;   // RNE
  return (unsigned short)r;
}
__device__ __forceinline__ u32 pack2(float a, float b) {
  return (u32)bf16_of(a) | ((u32)bf16_of(b) << 16);
}

// Threefry-2x32 (exact JAX rotation/key schedule) — constexpr-able so the
// layer keys fold to literals at compile time.
struct kp { u32 a, b; };
__host__ __device__ constexpr kp tfp(u32 k0, u32 k1, u32 x0, u32 x1) {
  u32 ks2 = k0 ^ k1 ^ 0x1BD11BDAu;
  x0 += k0; x1 += k1;
#define TFR(r) { x0 += x1; x1 = (x1 << (r)) | (x1 >> (32 - (r))); x1 ^= x0; }
  TFR(13) TFR(15) TFR(26) TFR(6)
  x0 += k1; x1 += ks2 + 1u;
  TFR(17) TFR(29) TFR(16) TFR(24)
  x0 += ks2; x1 += k0 + 2u;
  TFR(13) TFR(15) TFR(26) TFR(6)
  x0 += k0; x1 += k1 + 3u;
  TFR(17) TFR(29) TFR(16) TFR(24)
  x0 += k1; x1 += ks2 + 4u;
  TFR(13) TFR(15) TFR(26) TFR(6)
  x0 += ks2; x1 += k0 + 5u;
#undef TFR
  return kp{x0, x1};
}
// split(key(42)) partitionable: key_i = threefry((0,42), (0,i))
constexpr kp KEY1 = tfp(0u, 42u, 0u, 0u);
constexpr kp KEY2 = tfp(0u, 42u, 0u, 1u);

// per-element dropout keep decision (exact JAX): fold-xor, top-23 bits -> [0,1)
__device__ __forceinline__ bool keep_elem(u32 ka, u32 kb, u32 f) {
  kp h = tfp(ka, kb, 0u, f);
  u32 bitsv = h.a ^ h.b;
  float u = __uint_as_float((bitsv >> 9) | 0x3F800000u) - 1.0f;
  return u < 0.8f;
}

// bit->bf16 expansion: byte (8 bits, tau-permuted at build time) -> 8 bf16 {0,1}
// element e <- byte bit tau(e), tau=(0,2,1,3,4,6,5,7) self-inverse.
__device__ __forceinline__ short8 expand_byte(u32 byte) {
  u32 lo = byte & 15u, hi = (byte >> 4) & 15u;
  u32 s0 = (lo * 0x00204081u) & 0x01010101u;
  u32 s1 = (hi * 0x00204081u) & 0x01010101u;
  union { u32 u[4]; short8 v; } r;
  r.u[0] = (s0 & 0x00010001u) * 0x3F80u;
  r.u[1] = ((s0 >> 8) & 0x00010001u) * 0x3F80u;
  r.u[2] = (s1 & 0x00010001u) * 0x3F80u;
  r.u[3] = ((s1 >> 8) & 0x00010001u) * 0x3F80u;
  return r.v;
}

// ---------------- kernel 1: adj -> bitmask + dinv ----------
__global__ __launch_bounds__(256) void k_bits(const int* __restrict__ adj,
                                              u64* __restrict__ bits,
                                              float* __restrict__ dinv) {
  int row = blockIdx.x;              // b*N + i
  int i = row & (Nn - 1);
  int lane = threadIdx.x & 63;
  int wv = threadIdx.x >> 6;
  __shared__ int cnts[4];
  int col0 = wv * 1024 + lane * 16;  // first of 16 columns this thread owns
  const int4* rp = (const int4*)(adj + (size_t)row * Nn + col0);
  int4 a0 = rp[0];
  int4 a1 = rp[1];
  int4 a2 = rp[2];
  int4 a3 = rp[3];
  // tau bit positions for e=0..7: 0,2,1,3,4,6,5,7
  u32 v = 0;
  v |= (a0.x != 0) ? (1u << 0) : 0u;
  v |= (a0.y != 0) ? (1u << 2) : 0u;
  v |= (a0.z != 0) ? (1u << 1) : 0u;
  v |= (a0.w != 0) ? (1u << 3) : 0u;
  v |= (a1.x != 0) ? (1u << 4) : 0u;
  v |= (a1.y != 0) ? (1u << 6) : 0u;
  v |= (a1.z != 0) ? (1u << 5) : 0u;
  v |= (a1.w != 0) ? (1u << 7) : 0u;
  v |= (a2.x != 0) ? (1u << 8) : 0u;
  v |= (a2.y != 0) ? (1u << 10) : 0u;
  v |= (a2.z != 0) ? (1u << 9) : 0u;
  v |= (a2.w != 0) ? (1u << 11) : 0u;
  v |= (a3.x != 0) ? (1u << 12) : 0u;
  v |= (a3.y != 0) ? (1u << 14) : 0u;
  v |= (a3.z != 0) ? (1u << 13) : 0u;
  v |= (a3.w != 0) ? (1u << 15) : 0u;
  if ((i >> 4) == (col0 >> 4)) {     // self-loop column lands in my 16
    int e = i & 15;
    int e7 = e & 7;
    int m = ((e7 ^ (e7 >> 1)) & 1);
    int bit = (e & 8) + (e7 ^ (m * 3));   // (e&8) + tau(e&7)
    v |= 1u << bit;
  }
  ((unsigned short*)bits)[(size_t)row * 256 + (size_t)(wv * 64 + lane)] =
      (unsigned short)v;
  int c = __popc(v);
  c += __shfl_down(c, 32, 64);
  c += __shfl_down(c, 16, 64);
  c += __shfl_down(c, 8, 64);
  c += __shfl_down(c, 4, 64);
  c += __shfl_down(c, 2, 64);
  c += __shfl_down(c, 1, 64);
  if (lane == 0) cnts[wv] = c;
  __syncthreads();
  if (threadIdx.x == 0) {
    int deg = cnts[0] + cnts[1] + cnts[2] + cnts[3];
    dinv[row] = (float)(1.0 / sqrt((double)deg));
  }
}

// ---------------- kernel 2: Yt = swizzled-transpose( dinv .* (X @ W) ) bf16 ----
// Layer-1 only (reads x directly). 64-row tile per block; MFMA 16x16x32 bf16.
__global__ __launch_bounds__(256) void k_xw(const float* __restrict__ X,
                                            const float* __restrict__ W,
                                            const float* __restrict__ dinv,
                                            unsigned short* __restrict__ Yt) {
  __shared__ __align__(16) unsigned short Xl[64][72];  // +8 pad: stride 144B
  __shared__ __align__(16) unsigned short Wt[64][72];  // W transposed [d][k]
  __shared__ float dl[64];
  int tid = threadIdx.x;
  int gi0 = blockIdx.x * 64;            // global row b*N + i
#pragma unroll
  for (int it = 0; it < 8; ++it) {      // X tile: 2048 bf16-pairs
    int p = it * 256 + tid;
    int r = p >> 5, c2 = (p & 31) * 2;
    const float* src = X + (size_t)(gi0 + r) * Dd + c2;
    *(u32*)&Xl[r][c2] = pack2(src[0], src[1]);
  }
#pragma unroll
  for (int it = 0; it < 16; ++it) {     // W: 4096 elems, transposed into Wt[d][k]
    int e = it * 256 + tid;
    int k = e >> 6, d = e & 63;
    Wt[d][k] = bf16_of(W[e]);
  }
  if (tid < 64) dl[tid] = dinv[gi0 + tid];
  __syncthreads();

  int lane = tid & 63, wv = tid >> 6;
  int q = lane >> 4, ln = lane & 15;
  f32x4 acc[4];
#pragma unroll
  for (int t = 0; t < 4; ++t) { acc[t][0]=0.f; acc[t][1]=0.f; acc[t][2]=0.f; acc[t][3]=0.f; }
#pragma unroll
  for (int ks = 0; ks < 2; ++ks) {
    short8 a = *(short8*)&Xl[wv * 16 + ln][ks * 32 + q * 8];
#pragma unroll
    for (int t = 0; t < 4; ++t) {
      short8 bfr = *(short8*)&Wt[t * 16 + ln][ks * 32 + q * 8];
      acc[t] = __builtin_amdgcn_mfma_f32_16x16x32_bf16(a, bfr, acc[t], 0, 0, 0);
    }
  }
  int b = gi0 >> 12;
  int i_in_b = gi0 & (Nn - 1);
#pragma unroll
  for (int t = 0; t < 4; ++t) {
    int d = t * 16 + ln;
    int j0 = i_in_b + wv * 16 + q * 4;  // node index of first of 4 rows
    unsigned short h[4];
#pragma unroll
    for (int r = 0; r < 4; ++r) h[r] = bf16_of(acc[t][r] * dl[wv * 16 + q * 4 + r]);
    int byte0 = (2 * j0) & 511;
    int blk = (2 * j0) >> 9;
    size_t off = ((size_t)b * 64 + d) * (Nn * 2) + ((size_t)blk << 9)
               + (size_t)(byte0 ^ ((d & 7) << 4));     // XOR swizzle per d
    uint2 st; st.x = (u32)h[0] | ((u32)h[1] << 16); st.y = (u32)h[2] | ((u32)h[3] << 16);
    *(uint2*)((char*)Yt + off) = st;
  }
}

// ---------------- per-wave SpMM: barrier-free, LDS-free K-loop ----------------
// Wave wv owns K-slice [wv*512, (wv+1)*512) for the block's 32 rows x 64 d.
// B-fragments (16B/lane) loaded straight from the L2-resident Yt panel; the
// stored XOR swizzle folds to addr = base + ((p*64) ^ s6) with s6=(ln&4)<<4.
// A-fragments expanded from adjacency bit-bytes (tau-permuted at k_bits).
__device__ __forceinline__ void spmm_wave(const u64* __restrict__ bits,
                                          const char* __restrict__ ytp,
                                          int gi0, int wv, int lane,
                                          f32x4 acc[2][4]) {
  int q = lane >> 4, ln = lane & 15;
  const char* bb = (const char*)bits;
  const char* brow0 = bb + (size_t)(gi0 + ln) * 512 + (size_t)wv * 64;
  const char* brow1 = bb + (size_t)(gi0 + 16 + ln) * 512 + (size_t)wv * 64;
  int qx = (q * 16) ^ ((ln & 3) << 4);
  int s6 = (ln & 4) << 4;
  const char* base[4];
#pragma unroll
  for (int t = 0; t < 4; ++t)
    base[t] = ytp + (size_t)(t * 16 + ln) * (Nn * 2) + (size_t)wv * 1024 + qx;
#pragma unroll
  for (int pg = 0; pg < 4; ++pg) {      // 4 groups of 4 steps (16B of bits each)
    uint4 bw0 = *(const uint4*)(brow0 + pg * 16);
    uint4 bw1 = *(const uint4*)(brow1 + pg * 16);
    u32 ba0[4] = {bw0.x, bw0.y, bw0.z, bw0.w};
    u32 ba1[4] = {bw1.x, bw1.y, bw1.z, bw1.w};
#pragma unroll
    for (int p4 = 0; p4 < 4; ++p4) {    // step p: 32 K
      int p = pg * 4 + p4;
      short8 bf[4];
#pragma unroll
      for (int t = 0; t < 4; ++t)
        bf[t] = *(const short8*)(base[t] + ((p * 64) ^ s6));
      u32 by0 = (ba0[p4] >> (8 * q)) & 0xFFu;
      u32 by1 = (ba1[p4] >> (8 * q)) & 0xFFu;
      short8 a0 = expand_byte(by0);
      short8 a1 = expand_byte(by1);
#pragma unroll
      for (int t = 0; t < 4; ++t) {
        acc[0][t] = __builtin_amdgcn_mfma_f32_16x16x32_bf16(a0, bf[t], acc[0][t], 0, 0, 0);
        acc[1][t] = __builtin_amdgcn_mfma_f32_16x16x32_bf16(a1, bf[t], acc[1][t], 0, 0, 0);
      }
    }
  }
}

#define RED_STORE(buf)                                                        \
  {                                                                           \
    _Pragma("unroll") for (int s = 0; s < 2; ++s)                             \
    _Pragma("unroll") for (int t = 0; t < 4; ++t)                             \
    _Pragma("unroll") for (int r = 0; r < 4; ++r)                             \
        (buf)[s * 16 + q * 4 + r][t * 16 + ln] = acc[s][t][r];                \
  }
#define RED_ADD(buf)                                                          \
  {                                                                           \
    _Pragma("unroll") for (int s = 0; s < 2; ++s)                             \
    _Pragma("unroll") for (int t = 0; t < 4; ++t)                             \
    _Pragma("unroll") for (int r = 0; r < 4; ++r)                             \
        acc[s][t][r] += (buf)[s * 16 + q * 4 + r][t * 16 + ln];               \
  }

// ---------------- kernel 3: mega = spmm(full K) + epilogue + next-layer XW ----
// One block per 32 output rows; 512 thr = 8 waves = 8 K-slices. Barrier-free
// K-loop (see spmm_wave), then 8->1 LDS reduction tree, in-register epilogue
// (dinv*S+b, ELU, threefry dropout), then 32x64 H@W MFMA and swizzled bf16 Yt
// store for the NEXT layer.
__global__ __launch_bounds__(512, 4) void k_mega(const u64* __restrict__ bits,
                                                 const unsigned short* __restrict__ Ytin,
                                                 const float* __restrict__ W,
                                                 const float* __restrict__ dinv,
                                                 const float* __restrict__ bias,
                                                 unsigned short* __restrict__ Ytout,
                                                 u32 ka, u32 kb) {
  __shared__ __align__(16) float redb[4][32][68];       // 34.8 KB reduction tree
  __shared__ __align__(16) unsigned short Xl[32][72];
  __shared__ __align__(16) unsigned short Wt[64][72];
  __shared__ float dl[32];
  __shared__ float bl[64];
  int tid = threadIdx.x;
  int lane = tid & 63, wv = tid >> 6;
  int q = lane >> 4, ln = lane & 15;
  int gi0 = blockIdx.x * 32;            // flat row b*N + i
  int b = gi0 >> 12;

  // stage W (transposed, bf16), dinv, bias — no barrier needed until reduce
#pragma unroll
  for (int it = 0; it < 8; ++it) {
    int e = it * 512 + tid;
    Wt[e & 63][e >> 6] = bf16_of(W[e]);
  }
  if (tid < 32) dl[tid] = dinv[gi0 + tid];
  else if (tid < 96) bl[tid - 32] = bias[tid - 32];

  const char* ytp = (const char*)Ytin + (size_t)b * 64 * (Nn * 2);
  f32x4 acc[2][4];
#pragma unroll
  for (int s = 0; s < 2; ++s)
#pragma unroll
    for (int t = 0; t < 4; ++t) { acc[s][t][0]=0.f; acc[s][t][1]=0.f; acc[s][t][2]=0.f; acc[s][t][3]=0.f; }

  spmm_wave(bits, ytp, gi0, wv, lane, acc);

  // ---- 8-way reduction tree (4 LDS buffers) ----
  __syncthreads();
  if (wv >= 4) RED_STORE(redb[wv - 4]);
  __syncthreads();
  if (wv < 4) RED_ADD(redb[wv]);
  __syncthreads();
  if (wv == 2 || wv == 3) RED_STORE(redb[wv - 2]);
  __syncthreads();
  if (wv < 2) RED_ADD(redb[wv]);
  __syncthreads();
  if (wv == 1) RED_STORE(redb[0]);
  __syncthreads();
  if (wv == 0) { RED_ADD(redb[0]); RED_STORE(redb[1]); }
  __syncthreads();

  // ---- epilogue: all 8 waves, 4 elems/thread ----
  {
    int row = tid >> 4, d0 = (tid & 15) * 4;
    float dv = dl[row];
    f32x4 v0 = *(f32x4*)&redb[1][row][d0];
    float h2[4];
#pragma unroll
    for (int j = 0; j < 4; ++j) {
      float s = v0[j] * dv + bl[d0 + j];
      float el = s > 0.f ? s : expm1f(s);
      u32 f = (u32)((gi0 + row) * 64 + d0 + j);
      h2[j] = keep_elem(ka, kb, f) ? el * 1.25f : 0.f;  // /0.8 == *1.25
    }
    uint2 st; st.x = pack2(h2[0], h2[1]); st.y = pack2(h2[2], h2[3]);
    *(uint2*)&Xl[row][d0] = st;
  }
  __syncthreads();

  // ---- next-layer XW: 8 waves = strip2(2) x th(4), each 16 rows x 16 d ----
  {
    int strip2 = wv & 1, th = wv >> 1;
    f32x4 a2;
    a2[0]=0.f; a2[1]=0.f; a2[2]=0.f; a2[3]=0.f;
#pragma unroll
    for (int ks = 0; ks < 2; ++ks) {
      short8 a = *(short8*)&Xl[strip2 * 16 + ln][ks * 32 + q * 8];
      short8 bfr = *(short8*)&Wt[th * 16 + ln][ks * 32 + q * 8];
      a2 = __builtin_amdgcn_mfma_f32_16x16x32_bf16(a, bfr, a2, 0, 0, 0);
    }
    int i_in_b = gi0 & (Nn - 1);
    int d = th * 16 + ln;
    int j0 = i_in_b + strip2 * 16 + q * 4;
    unsigned short h[4];
#pragma unroll
    for (int r = 0; r < 4; ++r)
      h[r] = bf16_of(a2[r] * dl[strip2 * 16 + q * 4 + r]);
    int byte0 = (2 * j0) & 511;
    int blkk = (2 * j0) >> 9;
    size_t off = ((size_t)b * 64 + d) * (Nn * 2) + ((size_t)blkk << 9)
               + (size_t)(byte0 ^ ((d & 7) << 4));
    uint2 st; st.x = (u32)h[0] | ((u32)h[1] << 16); st.y = (u32)h[2] | ((u32)h[3] << 16);
    *(uint2*)((char*)Ytout + off) = st;
  }
}

// ---------------- kernel 4: final = spmm(full K) + dinv*S + bias -> out ------
__global__ __launch_bounds__(512, 4) void k_fin(const u64* __restrict__ bits,
                                                const unsigned short* __restrict__ Ytin,
                                                const float* __restrict__ dinv,
                                                const float* __restrict__ bias,
                                                float* __restrict__ out) {
  __shared__ __align__(16) float redb[4][32][68];
  __shared__ float dl[32];
  __shared__ float bl[64];
  int tid = threadIdx.x;
  int lane = tid & 63, wv = tid >> 6;
  int q = lane >> 4, ln = lane & 15;
  int gi0 = blockIdx.x * 32;
  int b = gi0 >> 12;

  if (tid < 32) dl[tid] = dinv[gi0 + tid];
  else if (tid < 96) bl[tid - 32] = bias[tid - 32];

  const char* ytp = (const char*)Ytin + (size_t)b * 64 * (Nn * 2);
  f32x4 acc[2][4];
#pragma unroll
  for (int s = 0; s < 2; ++s)
#pragma unroll
    for (int t = 0; t < 4; ++t) { acc[s][t][0]=0.f; acc[s][t][1]=0.f; acc[s][t][2]=0.f; acc[s][t][3]=0.f; }

  spmm_wave(bits, ytp, gi0, wv, lane, acc);

  __syncthreads();
  if (wv >= 4) RED_STORE(redb[wv - 4]);
  __syncthreads();
  if (wv < 4) RED_ADD(redb[wv]);
  __syncthreads();
  if (wv == 2 || wv == 3) RED_STORE(redb[wv - 2]);
  __syncthreads();
  if (wv < 2) RED_ADD(redb[wv]);
  __syncthreads();
  if (wv == 1) RED_STORE(redb[0]);
  __syncthreads();
  if (wv == 0) { RED_ADD(redb[0]); RED_STORE(redb[1]); }
  __syncthreads();

  {
    int row = tid >> 4, d0 = (tid & 15) * 4;
    float dv = dl[row];
    f32x4 v0 = *(f32x4*)&redb[1][row][d0];
    float4 o;
    o.x = v0[0] * dv + bl[d0 + 0];
    o.y = v0[1] * dv + bl[d0 + 1];
    o.z = v0[2] * dv + bl[d0 + 2];
    o.w = v0[3] * dv + bl[d0 + 3];
    *(float4*)(out + (size_t)(gi0 + row) * 64 + d0) = o;
  }
}

// ---------------- launch ----------------
extern "C" void kernel_launch(void* const* d_in, const int* in_sizes, int n_in,
                              void* d_out, int out_size, void* d_ws, size_t ws_size,
                              hipStream_t stream) {
  const float* x  = (const float*)d_in[0];
  const int*   adj= (const int*)d_in[1];
  const float* W1 = (const float*)d_in[2];
  const float* b1 = (const float*)d_in[3];
  const float* W2 = (const float*)d_in[4];
  const float* b2 = (const float*)d_in[5];
  const float* W3 = (const float*)d_in[6];
  const float* b3 = (const float*)d_in[7];
  float* out = (float*)d_out;
  char* ws = (char*)d_ws;

  u64*            bits = (u64*)(ws);                         // 8,388,608 B
  float*          dinv = (float*)(ws + 8388608);             //    65,536 B
  unsigned short* YtA  = (unsigned short*)(ws + 8454144);    // 2,097,152 B
  unsigned short* YtB  = (unsigned short*)(ws + 10551296);   // 2,097,152 B

  k_bits<<<Bsz * Nn, 256, 0, stream>>>(adj, bits, dinv);

  // layer 1 XW
  k_xw<<<(Bsz * Nn) / 64, 256, 0, stream>>>(x, W1, dinv, YtA);
  // layer 1 aggregate + epilogue + layer 2 XW
  k_mega<<<(Bsz * Nn) / 32, 512, 0, stream>>>(bits, YtA, W2, dinv, b1, YtB,
                                              KEY1.a, KEY1.b);
  // layer 2 aggregate + epilogue + layer 3 XW
  k_mega<<<(Bsz * Nn) / 32, 512, 0, stream>>>(bits, YtB, W3, dinv, b2, YtA,
                                              KEY2.a, KEY2.b);
  // layer 3 aggregate + bias -> out
  k_fin<<<(Bsz * Nn) / 32, 512, 0, stream>>>(bits, YtA, dinv, b3, out);
}